// Round 10
// baseline (68.664 us; speedup 1.0000x reference)
//
#include <hip/hip_runtime.h>
#include <stdint.h>

#define S_GRID 7
#define N_CH 30
#define MAXB 8192          // max compacted boxes (actual data: 6272)
#define NTILE 32           // final j-tiles (256 cols each)
#define NCHUNK 16          // i-chunks in match
#define JG 8               // j-columns per wave in k_match

// ---- ws layout (bytes) ----
// 0      : float acc[4] {xy+wh, obj, nobj, class}
// 16     : int ctr        (obj-cell allocator)
// 20     : int finalCtr
// 1024   : u64 maxkey[MAXB]  (65536) -> 66560
// 66560  : float4 BP[MAXB]   (131072) -> 197632
// 197632 : float4 BT[MAXB]   (131072) -> 328704
// 328704 : float  ConfP[MAXB] (32768) -> 361472
// 361472 : float  AreaP[MAXB] (32768) -> 394240

__global__ void k_init(float* __restrict__ acc, int* __restrict__ ctr, int* __restrict__ finalCtr) {
    if (threadIdx.x < 4)  acc[threadIdx.x] = 0.0f;
    if (threadIdx.x == 4) *ctr = 0;
    if (threadIdx.x == 5) *finalCtr = 0;
}

// one pass over P,T: unordered compaction (wave-aggregated atomic alloc, proven absmax=0 in R4)
// + cheap masked losses straight into pre-zeroed acc + maxkey zeroing spread across the grid.
__global__ void k_prep(const float* __restrict__ P, const float* __restrict__ T, int ncell,
                       int* __restrict__ ctr,
                       float4* __restrict__ BP, float4* __restrict__ BT,
                       float* __restrict__ ConfP, float* __restrict__ AreaP,
                       float* __restrict__ acc,
                       unsigned long long* __restrict__ maxkey) {
    int gid = blockIdx.x * 256 + threadIdx.x;
    if (gid < MAXB) maxkey[gid] = 0ull;      // plain store; visible to k_match at boundary

    int cell = gid;
    const float* p = P + (size_t)cell * N_CH;
    const float* t = T + (size_t)cell * N_CH;
    bool obj = (cell < ncell) && (t[4] == 1.0f);

    int lane = threadIdx.x & 63;
    unsigned long long bm = __ballot(obj);
    int wcnt = __popcll(bm);
    int base = 0;
    if (lane == 0 && wcnt) base = atomicAdd(ctr, wcnt);
    base = __shfl(base, 0);

    float cls = 0.f, nob = 0.f;
    if (cell < ncell) {
        if (obj) {
            #pragma unroll
            for (int k = 10; k < 30; k++) { float d = p[k] - t[k]; cls += d * d; }
        } else {
            float d0 = p[4] - t[4], d1 = p[9] - t[9];
            nob = d0 * d0 + d1 * d1;
        }
    }
    #pragma unroll
    for (int o = 32; o; o >>= 1) { cls += __shfl_down(cls, o); nob += __shfl_down(nob, o); }
    if (lane == 0) {
        if (cls != 0.f) atomicAdd(&acc[3], cls);
        if (nob != 0.f) atomicAdd(&acc[2], nob);
    }

    if (obj) {
        int rank = base + __popcll(bm & ((1ull << lane) - 1ull));
        #pragma unroll
        for (int bb = 0; bb < 2; ++bb) {
            int m = 2 * rank + bb;
            if (m < MAXB) {
                int o5 = bb * 5;
                float cx = p[o5 + 0] / (float)S_GRID, cy = p[o5 + 1] / (float)S_GRID;
                float w = p[o5 + 2], h = p[o5 + 3];
                float4 bp = make_float4(cx - 0.5f * w, cy - 0.5f * h, cx + 0.5f * w, cy + 0.5f * h);
                BP[m] = bp;
                AreaP[m] = (bp.z - bp.x) * (bp.w - bp.y);
                ConfP[m] = p[4 + o5];
                cx = t[o5 + 0] / (float)S_GRID; cy = t[o5 + 1] / (float)S_GRID;
                w = t[o5 + 2]; h = t[o5 + 3];
                BT[m] = make_float4(cx - 0.5f * w, cy - 0.5f * h, cx + 0.5f * w, cy + 0.5f * h);
            }
        }
    }
}

// wave-centric match: lane l streams box i0+l (coalesced VECTOR loads, VALU-bound);
// each wave holds JG target boxes wave-uniform. Divide-free running argmax; shuffle
// max-reduce; lane 0 publishes via atomicMax (deterministic: max of deterministic keys).
__global__ void k_match(const float4* __restrict__ BP, const float4* __restrict__ BT,
                        const float* __restrict__ AreaP,
                        const int* __restrict__ ctr,
                        unsigned long long* __restrict__ maxkey) {
    int nb = 2 * (*ctr); if (nb > MAXB) nb = MAXB;
    int lane = threadIdx.x & 63, wid = threadIdx.x >> 6;
    int wgrp = blockIdx.x * 4 + wid;         // JG consecutive j's per wave
    int j0 = wgrp * JG;
    int c = blockIdx.y;
    int chunkLen = (nb + NCHUNK - 1) / NCHUNK;
    int i0 = c * chunkLen;
    int i1 = min(nb, i0 + chunkLen);
    if (j0 >= nb || i0 >= i1) return;

    float4 tb[JG]; float ta[JG];
    #pragma unroll
    for (int jj = 0; jj < JG; ++jj) {
        float4 t = BT[min(j0 + jj, nb - 1)]; // wave-uniform -> scalar regs
        tb[jj] = t;
        ta[jj] = (t.z - t.x) * (t.w - t.y);
    }
    float bestN[JG], bestD[JG]; int bidx[JG];
    #pragma unroll
    for (int jj = 0; jj < JG; ++jj) { bestN[jj] = -1.f; bestD[jj] = 1.f; bidx[jj] = 0; }

    for (int ib = i0; ib < i1; ib += 64) {
        int i = ib + lane;
        bool v = i < i1;
        int ic = v ? i : i1 - 1;             // clamped load, guarded update
        float4 pb = BP[ic];
        float a1 = AreaP[ic];
        #pragma unroll
        for (int jj = 0; jj < JG; ++jj) {
            float lx = fmaxf(pb.x, tb[jj].x), ly = fmaxf(pb.y, tb[jj].y);
            float rx = fminf(pb.z, tb[jj].z), ry = fminf(pb.w, tb[jj].w);
            float wx = fmaxf(rx - lx, 0.f), wy = fmaxf(ry - ly, 0.f);
            float inter = wx * wy;
            float u = (a1 + ta[jj]) - inter;
            bool win = v && (inter * bestD[jj] > bestN[jj] * u);
            bestN[jj] = win ? inter : bestN[jj];
            bestD[jj] = win ? u : bestD[jj];
            bidx[jj]  = win ? i : bidx[jj];
        }
    }

    #pragma unroll
    for (int jj = 0; jj < JG; ++jj) {
        unsigned long long key = 0;          // invalid lanes contribute 0 (< any valid key)
        if (bestN[jj] >= 0.f) {
            float r;                         // approx rcp: rel err ~1e-7; threshold 0.89 abs
            asm("v_rcp_f32 %0, %1" : "=v"(r) : "v"(bestD[jj]));
            float best = bestN[jj] * r;
            key = ((unsigned long long)__float_as_uint(best) << 32) |
                  (unsigned long long)(0xFFFFFFFFu - (unsigned)bidx[jj]);
        }
        #pragma unroll
        for (int o = 32; o; o >>= 1) {       // max-reduce to lane 0 (ties -> smaller idx)
            unsigned lo = (unsigned)key, hi = (unsigned)(key >> 32);
            unsigned lo2 = (unsigned)__shfl_down((int)lo, o);
            unsigned hi2 = (unsigned)__shfl_down((int)hi, o);
            unsigned long long other = ((unsigned long long)hi2 << 32) | lo2;
            if (other > key) key = other;
        }
        if (lane == 0 && j0 + jj < nb)
            atomicMax(&maxkey[j0 + jj], key);
    }
}

// final: read per-j winner, box/conf losses, reduce, ACQ_REL election, write scalar
__global__ void k_final(const float4* __restrict__ BP, const float4* __restrict__ BT,
                        const float* __restrict__ ConfP,
                        const int* __restrict__ ctr,
                        const unsigned long long* __restrict__ maxkey,
                        float* __restrict__ acc, int* __restrict__ finalCtr,
                        float* __restrict__ out, float inv_batch) {
    int nb = 2 * (*ctr); if (nb > MAXB) nb = MAXB;
    int tid = threadIdx.x;
    int j = blockIdx.x * 256 + tid;
    float sxywh = 0.f, sobj = 0.f;
    if (j < nb) {
        unsigned long long key = maxkey[j];
        float iou = __uint_as_float((unsigned)(key >> 32));
        unsigned idx = 0xFFFFFFFFu - (unsigned)(key & 0xFFFFFFFFull);
        float4 bp = BP[idx], bt = BT[idx];
        float cp = ConfP[idx];
        float dx = bp.x - bt.x, dy = bp.y - bt.y;
        float dw = sqrtf(bp.z) - sqrtf(bt.z);
        float dh = sqrtf(bp.w) - sqrtf(bt.w);
        sxywh = dx * dx + dy * dy + dw * dw + dh * dh;
        float dob = cp - iou;
        sobj = dob * dob;
    }
    #pragma unroll
    for (int o = 32; o; o >>= 1) { sxywh += __shfl_down(sxywh, o); sobj += __shfl_down(sobj, o); }
    if ((tid & 63) == 0) {
        if (sxywh != 0.f) atomicAdd(&acc[0], sxywh);
        if (sobj != 0.f)  atomicAdd(&acc[1], sobj);
    }
    __syncthreads();                         // drains wave-leader atomics
    if (tid == 0) {
        int old = __hip_atomic_fetch_add(finalCtr, 1, __ATOMIC_ACQ_REL, __HIP_MEMORY_SCOPE_AGENT);
        if (old == NTILE - 1) {              // last block: all adds visible
            float a0 = __hip_atomic_load(&acc[0], __ATOMIC_RELAXED, __HIP_MEMORY_SCOPE_AGENT);
            float a1 = __hip_atomic_load(&acc[1], __ATOMIC_RELAXED, __HIP_MEMORY_SCOPE_AGENT);
            float a2 = __hip_atomic_load(&acc[2], __ATOMIC_RELAXED, __HIP_MEMORY_SCOPE_AGENT);
            float a3 = __hip_atomic_load(&acc[3], __ATOMIC_RELAXED, __HIP_MEMORY_SCOPE_AGENT);
            out[0] = (5.0f * a0 + 0.5f * a2 + a1 + a3) * inv_batch;
        }
    }
}

extern "C" void kernel_launch(void* const* d_in, const int* in_sizes, int n_in,
                              void* d_out, int out_size, void* d_ws, size_t ws_size,
                              hipStream_t stream) {
    const float* P = (const float*)d_in[0];
    const float* T = (const float*)d_in[1];
    int ncell = in_sizes[0] / N_CH;                 // 25088
    int batch = ncell / (S_GRID * S_GRID);          // 512

    char* ws = (char*)d_ws;
    float* acc      = (float*)ws;
    int*   ctr      = (int*)(ws + 16);
    int*   finalCtr = (int*)(ws + 20);
    unsigned long long* maxkey = (unsigned long long*)(ws + 1024);
    float4* BP    = (float4*)(ws + 66560);
    float4* BT    = (float4*)(ws + 197632);
    float*  ConfP = (float*)(ws + 328704);
    float*  AreaP = (float*)(ws + 361472);

    int nblk = (ncell + 255) / 256;                 // 98
    k_init <<<1, 64, 0, stream>>>(acc, ctr, finalCtr);
    k_prep <<<nblk, 256, 0, stream>>>(P, T, ncell, ctr, BP, BT, ConfP, AreaP, acc, maxkey);
    dim3 g3(MAXB / (4 * JG), NCHUNK);               // (256, 16); idle groups exit
    k_match<<<g3, 256, 0, stream>>>(BP, BT, AreaP, ctr, maxkey);
    k_final<<<NTILE, 256, 0, stream>>>(BP, BT, ConfP, ctr, maxkey, acc, finalCtr,
                                       (float*)d_out, 1.0f / (float)batch);
}

// Round 12
// 63.042 us; speedup vs baseline: 1.0892x; 1.0892x over previous
//
#include <hip/hip_runtime.h>
#include <stdint.h>

#define S_GRID 7
#define N_CH 30
#define MAXB 8192          // max compacted boxes (actual data: 6272)
#define NTILE 32           // final j-tiles (256 cols each)
#define NCHUNK 80          // i-chunks in match (~7900 active waves ~= 7.7/SIMD)

typedef float float8 __attribute__((ext_vector_type(8)));

// ---- ws layout (bytes) ----
// 0      : float acc[4] {xy+wh, obj, nobj, class}
// 16     : int ctr        (obj-cell allocator)
// 20     : int finalCtr
// 1024   : u64 maxkey[MAXB]            (65536)  -> 66560
// 66560  : float8 PB8[MAXB] {x0,y0,x1,y1,area,conf,0,0}  (262144) -> 328704
// 328704 : float4 BT4[MAXB]            (131072) -> 459776

__global__ void k_init(float* __restrict__ acc, int* __restrict__ ctr, int* __restrict__ finalCtr) {
    if (threadIdx.x < 4)  acc[threadIdx.x] = 0.0f;
    if (threadIdx.x == 4) *ctr = 0;
    if (threadIdx.x == 5) *finalCtr = 0;
}

// one pass over P,T: unordered compaction (wave-aggregated atomic alloc; absmax=0 in R4/R10)
// + cheap masked losses into pre-zeroed acc + maxkey zeroing spread across the grid.
__global__ void k_prep(const float* __restrict__ P, const float* __restrict__ T, int ncell,
                       int* __restrict__ ctr,
                       float8* __restrict__ PB8, float4* __restrict__ BT4,
                       float* __restrict__ acc,
                       unsigned long long* __restrict__ maxkey) {
    int gid = blockIdx.x * 256 + threadIdx.x;
    if (gid < MAXB) maxkey[gid] = 0ull;      // plain store; visible to k_match at boundary

    int cell = gid;
    const float* p = P + (size_t)cell * N_CH;
    const float* t = T + (size_t)cell * N_CH;
    bool obj = (cell < ncell) && (t[4] == 1.0f);

    int lane = threadIdx.x & 63;
    unsigned long long bm = __ballot(obj);
    int wcnt = __popcll(bm);
    int base = 0;
    if (lane == 0 && wcnt) base = atomicAdd(ctr, wcnt);
    base = __shfl(base, 0);

    float cls = 0.f, nob = 0.f;
    if (cell < ncell) {
        if (obj) {
            #pragma unroll
            for (int k = 10; k < 30; k++) { float d = p[k] - t[k]; cls += d * d; }
        } else {
            float d0 = p[4] - t[4], d1 = p[9] - t[9];
            nob = d0 * d0 + d1 * d1;
        }
    }
    #pragma unroll
    for (int o = 32; o; o >>= 1) { cls += __shfl_down(cls, o); nob += __shfl_down(nob, o); }
    if (lane == 0) {
        if (cls != 0.f) atomicAdd(&acc[3], cls);
        if (nob != 0.f) atomicAdd(&acc[2], nob);
    }

    if (obj) {
        int rank = base + __popcll(bm & ((1ull << lane) - 1ull));
        #pragma unroll
        for (int bb = 0; bb < 2; ++bb) {
            int m = 2 * rank + bb;
            if (m < MAXB) {
                int o5 = bb * 5;
                float cx = p[o5 + 0] / (float)S_GRID, cy = p[o5 + 1] / (float)S_GRID;
                float w = p[o5 + 2], h = p[o5 + 3];
                float8 v;
                v[0] = cx - 0.5f * w; v[1] = cy - 0.5f * h;
                v[2] = cx + 0.5f * w; v[3] = cy + 0.5f * h;
                v[4] = (v[2] - v[0]) * (v[3] - v[1]);   // area
                v[5] = p[4 + o5];                        // conf
                v[6] = 0.f; v[7] = 0.f;
                PB8[m] = v;
                cx = t[o5 + 0] / (float)S_GRID; cy = t[o5 + 1] / (float)S_GRID;
                w = t[o5 + 2]; h = t[o5 + 3];
                BT4[m] = make_float4(cx - 0.5f * w, cy - 0.5f * h, cx + 0.5f * w, cy + 0.5f * h);
            }
        }
    }
}

// j-per-LANE match: each lane owns one target box (tb in VGPRs); i-boxes stream
// wave-uniform via s_load_dwordx8 (scalar operands are free in VALU), 4-deep
// software pipeline. q-transform compare: iou_i > iou_best <=> inter > q*sum,
// q = inter/(a1+a2) (monotone in iou since union = sum - inter). rcp only on win.
__global__ void k_match(const float8* __restrict__ PB8, const float4* __restrict__ BT4,
                        const int* __restrict__ ctr,
                        unsigned long long* __restrict__ maxkey) {
    int nb = 2 * (*ctr); if (nb > MAXB) nb = MAXB;
    int tid = threadIdx.x;
    int j = blockIdx.x * 256 + tid;
    if (blockIdx.x * 256 >= nb) return;      // whole tile beyond nb
    int c = blockIdx.y;
    int chunkLen = (((nb + NCHUNK - 1) / NCHUNK) + 3) & ~3;   // multiple of 4
    int i0 = c * chunkLen;
    int i1 = min(nb, i0 + chunkLen);
    if (i0 >= i1) return;

    float4 tb = BT4[min(j, nb - 1)];         // per-lane target box
    float ta = (tb.z - tb.x) * (tb.w - tb.y);
    float q = -1.f, bI = -1.f, bS = 1.f;     // first valid box always wins (q*sum<0<=inter)
    int bidx = 0;

    float8 n0 = PB8[i0], n1 = PB8[i0 + 1], n2 = PB8[i0 + 2], n3 = PB8[i0 + 3];
    for (int ib = i0; ib < i1; ib += 4) {
        float8 c0 = n0, c1 = n1, c2 = n2, c3 = n3;
        int nx = ib + 4;
        if (nx < i1) { n0 = PB8[nx]; n1 = PB8[nx + 1]; n2 = PB8[nx + 2]; n3 = PB8[nx + 3]; }
        #define STEP(cc, kk)  {                                                     \
            float lx = fmaxf(tb.x, cc[0]), ly = fmaxf(tb.y, cc[1]);                 \
            float rx = fminf(tb.z, cc[2]), ry = fminf(tb.w, cc[3]);                 \
            float wx = fmaxf(rx - lx, 0.f), wy = fmaxf(ry - ly, 0.f);               \
            float inter = wx * wy;                                                  \
            float sum = ta + cc[4];                                                 \
            if (ib + kk < i1) {               /* wave-uniform guard */              \
                if (inter > q * sum) {        /* divergent, rare after warmup */    \
                    float r; asm("v_rcp_f32 %0, %1" : "=v"(r) : "v"(sum));          \
                    q = inter * r; bI = inter; bS = sum; bidx = ib + kk;            \
                }                                                                   \
            } }
        STEP(c0, 0) STEP(c1, 1) STEP(c2, 2) STEP(c3, 3)
        #undef STEP
    }

    if (j < nb && bI >= 0.f) {
        float iou = bI / (bS - bI);          // precise divide, once per lane per chunk
        unsigned long long key =
            ((unsigned long long)__float_as_uint(iou) << 32) |
            (unsigned long long)(0xFFFFFFFFu - (unsigned)bidx);
        atomicMax(&maxkey[j], key);          // bigger iou wins; ties -> smaller idx
    }
}

// final: read per-j winner, box/conf losses, reduce, ACQ_REL election, write scalar.
// NOTE: the reference gathers BOTH boxes by the argmax index: BPg=BP[idx], BTg=BT[idx]
// (R11's bug was BT4[j] here).
__global__ void k_final(const float8* __restrict__ PB8, const float4* __restrict__ BT4,
                        const int* __restrict__ ctr,
                        const unsigned long long* __restrict__ maxkey,
                        float* __restrict__ acc, int* __restrict__ finalCtr,
                        float* __restrict__ out, float inv_batch) {
    int nb = 2 * (*ctr); if (nb > MAXB) nb = MAXB;
    int tid = threadIdx.x;
    int j = blockIdx.x * 256 + tid;
    float sxywh = 0.f, sobj = 0.f;
    if (j < nb) {
        unsigned long long key = maxkey[j];
        float iou = __uint_as_float((unsigned)(key >> 32));
        unsigned idx = 0xFFFFFFFFu - (unsigned)(key & 0xFFFFFFFFull);
        float8 pb = PB8[idx];
        float4 bt = BT4[idx];                // <- by idx, matching the reference
        float dx = pb[0] - bt.x, dy = pb[1] - bt.y;
        float dw = sqrtf(pb[2]) - sqrtf(bt.z);
        float dh = sqrtf(pb[3]) - sqrtf(bt.w);
        sxywh = dx * dx + dy * dy + dw * dw + dh * dh;
        float dob = pb[5] - iou;
        sobj = dob * dob;
    }
    #pragma unroll
    for (int o = 32; o; o >>= 1) { sxywh += __shfl_down(sxywh, o); sobj += __shfl_down(sobj, o); }
    if ((tid & 63) == 0) {
        if (sxywh != 0.f) atomicAdd(&acc[0], sxywh);
        if (sobj != 0.f)  atomicAdd(&acc[1], sobj);
    }
    __syncthreads();                         // drains wave-leader atomics
    if (tid == 0) {
        int old = __hip_atomic_fetch_add(finalCtr, 1, __ATOMIC_ACQ_REL, __HIP_MEMORY_SCOPE_AGENT);
        if (old == NTILE - 1) {              // last block: all adds visible
            float a0 = __hip_atomic_load(&acc[0], __ATOMIC_RELAXED, __HIP_MEMORY_SCOPE_AGENT);
            float a1 = __hip_atomic_load(&acc[1], __ATOMIC_RELAXED, __HIP_MEMORY_SCOPE_AGENT);
            float a2 = __hip_atomic_load(&acc[2], __ATOMIC_RELAXED, __HIP_MEMORY_SCOPE_AGENT);
            float a3 = __hip_atomic_load(&acc[3], __ATOMIC_RELAXED, __HIP_MEMORY_SCOPE_AGENT);
            out[0] = (5.0f * a0 + 0.5f * a2 + a1 + a3) * inv_batch;
        }
    }
}

extern "C" void kernel_launch(void* const* d_in, const int* in_sizes, int n_in,
                              void* d_out, int out_size, void* d_ws, size_t ws_size,
                              hipStream_t stream) {
    const float* P = (const float*)d_in[0];
    const float* T = (const float*)d_in[1];
    int ncell = in_sizes[0] / N_CH;                 // 25088
    int batch = ncell / (S_GRID * S_GRID);          // 512

    char* ws = (char*)d_ws;
    float* acc      = (float*)ws;
    int*   ctr      = (int*)(ws + 16);
    int*   finalCtr = (int*)(ws + 20);
    unsigned long long* maxkey = (unsigned long long*)(ws + 1024);
    float8* PB8 = (float8*)(ws + 66560);
    float4* BT4 = (float4*)(ws + 328704);

    int nblk = (ncell + 255) / 256;                 // 98
    k_init <<<1, 64, 0, stream>>>(acc, ctr, finalCtr);
    k_prep <<<nblk, 256, 0, stream>>>(P, T, ncell, ctr, PB8, BT4, acc, maxkey);
    dim3 g3(NTILE, NCHUNK);                         // (32, 80); inactive blocks exit
    k_match<<<g3, 256, 0, stream>>>(PB8, BT4, ctr, maxkey);
    k_final<<<NTILE, 256, 0, stream>>>(PB8, BT4, ctr, maxkey, acc, finalCtr,
                                       (float*)d_out, 1.0f / (float)batch);
}

// Round 13
// 59.172 us; speedup vs baseline: 1.1604x; 1.0654x over previous
//
#include <hip/hip_runtime.h>
#include <stdint.h>

#define S_GRID 7
#define N_CH 30
#define MAXB 8192          // max compacted boxes (actual data: 6272)
#define NTILE 32           // final j-tiles (256 cols each)
#define NCHUNK 80          // i-chunks in match

typedef float float8 __attribute__((ext_vector_type(8)));

// ---- ws layout (bytes) ----
// 0      : float acc[4] {xy+wh, obj, nobj, class}
// 16     : int ctr        (obj-cell allocator)
// 20     : int finalCtr
// 1024   : u64 maxkey[MAXB]            (65536)  -> 66560
// 66560  : float8 PB8[MAXB] {x0,y0,x1,y1,area,conf,0,0}  (262144) -> 328704
// 328704 : float4 BT4[MAXB]            (131072) -> 459776

__global__ void k_init(float* __restrict__ acc, int* __restrict__ ctr, int* __restrict__ finalCtr) {
    if (threadIdx.x < 4)  acc[threadIdx.x] = 0.0f;
    if (threadIdx.x == 4) *ctr = 0;
    if (threadIdx.x == 5) *finalCtr = 0;
}

// one pass over P,T: unordered compaction (wave-aggregated atomic alloc; absmax=0 R4/R10/R12)
// + cheap masked losses into pre-zeroed acc + maxkey zeroing. Rows loaded as float2[15]
// (120B rows are 8B-aligned) -> uniform, non-divergent load stream.
__global__ void k_prep(const float* __restrict__ P, const float* __restrict__ T, int ncell,
                       int* __restrict__ ctr,
                       float8* __restrict__ PB8, float4* __restrict__ BT4,
                       float* __restrict__ acc,
                       unsigned long long* __restrict__ maxkey) {
    int gid = blockIdx.x * 256 + threadIdx.x;
    if (gid < MAXB) maxkey[gid] = 0ull;      // plain store; visible to k_match at boundary

    int cell = gid;
    float2 pr[15], tr[15];
    if (cell < ncell) {
        const float2* p2 = (const float2*)(P + (size_t)cell * N_CH);
        const float2* t2 = (const float2*)(T + (size_t)cell * N_CH);
        #pragma unroll
        for (int k = 0; k < 15; ++k) { pr[k] = p2[k]; tr[k] = t2[k]; }
    } else {
        #pragma unroll
        for (int k = 0; k < 15; ++k) { pr[k] = make_float2(0.f, 0.f); tr[k] = make_float2(0.f, 0.f); }
    }
    bool obj = (cell < ncell) && (tr[2].x == 1.0f);   // t[4]

    int lane = threadIdx.x & 63;
    unsigned long long bm = __ballot(obj);
    int wcnt = __popcll(bm);
    int base = 0;
    if (lane == 0 && wcnt) base = atomicAdd(ctr, wcnt);
    base = __shfl(base, 0);

    float cls = 0.f, nob = 0.f;
    if (cell < ncell) {
        if (obj) {
            #pragma unroll
            for (int k = 5; k < 15; ++k) {            // floats 10..29
                float d0 = pr[k].x - tr[k].x, d1 = pr[k].y - tr[k].y;
                cls += d0 * d0 + d1 * d1;
            }
        } else {
            float d0 = pr[2].x - tr[2].x;             // p[4]-t[4]
            float d1 = pr[4].y - tr[4].y;             // p[9]-t[9]
            nob = d0 * d0 + d1 * d1;
        }
    }
    #pragma unroll
    for (int o = 32; o; o >>= 1) { cls += __shfl_down(cls, o); nob += __shfl_down(nob, o); }
    if (lane == 0) {
        if (cls != 0.f) atomicAdd(&acc[3], cls);
        if (nob != 0.f) atomicAdd(&acc[2], nob);
    }

    if (obj) {
        int rank = base + __popcll(bm & ((1ull << lane) - 1ull));
        // box floats: bb=0 -> f0..f4 ; bb=1 -> f5..f9
        float bx[2][5] = {
            { pr[0].x, pr[0].y, pr[1].x, pr[1].y, pr[2].x },
            { pr[2].y, pr[3].x, pr[3].y, pr[4].x, pr[4].y }
        };
        float tx[2][4] = {
            { tr[0].x, tr[0].y, tr[1].x, tr[1].y },
            { tr[2].y, tr[3].x, tr[3].y, tr[4].x }
        };
        #pragma unroll
        for (int bb = 0; bb < 2; ++bb) {
            int m = 2 * rank + bb;
            if (m < MAXB) {
                float cx = bx[bb][0] / (float)S_GRID, cy = bx[bb][1] / (float)S_GRID;
                float w = bx[bb][2], h = bx[bb][3];
                float8 v;
                v[0] = cx - 0.5f * w; v[1] = cy - 0.5f * h;
                v[2] = cx + 0.5f * w; v[3] = cy + 0.5f * h;
                v[4] = (v[2] - v[0]) * (v[3] - v[1]);   // area
                v[5] = bx[bb][4];                        // conf
                v[6] = 0.f; v[7] = 0.f;
                PB8[m] = v;
                cx = tx[bb][0] / (float)S_GRID; cy = tx[bb][1] / (float)S_GRID;
                w = tx[bb][2]; h = tx[bb][3];
                BT4[m] = make_float4(cx - 0.5f * w, cy - 0.5f * h, cx + 0.5f * w, cy + 0.5f * h);
            }
        }
    }
}

// j-per-LANE match, BRANCHLESS + DIVISION-FREE inner loop:
//   iou_i > iou_best  <=>  inter_i * bS > bI * sum_i     (union = sum - inter)
// 2 mul + cmp + 3 cndmask per box; no rcp, no divergence, no loop-carried latency op.
// i-boxes stream wave-uniform via s_load_dwordx8, 4-deep pipeline.
__global__ void k_match(const float8* __restrict__ PB8, const float4* __restrict__ BT4,
                        const int* __restrict__ ctr,
                        unsigned long long* __restrict__ maxkey) {
    int nb = 2 * (*ctr); if (nb > MAXB) nb = MAXB;
    int tid = threadIdx.x;
    int j = blockIdx.x * 256 + tid;
    if (blockIdx.x * 256 >= nb) return;      // whole tile beyond nb
    int c = blockIdx.y;
    int chunkLen = (((nb + NCHUNK - 1) / NCHUNK) + 3) & ~3;   // multiple of 4
    int i0 = c * chunkLen;
    int i1 = min(nb, i0 + chunkLen);
    if (i0 >= i1) return;

    float4 tb = BT4[min(j, nb - 1)];         // per-lane target box
    float ta = (tb.z - tb.x) * (tb.w - tb.y);
    float bI = -1.f, bS = 1.f;               // first valid box always wins: inter*1 > -1*sum
    int bidx = 0;

    float8 n0 = PB8[i0], n1 = PB8[i0 + 1], n2 = PB8[i0 + 2], n3 = PB8[i0 + 3];
    for (int ib = i0; ib < i1; ib += 4) {
        float8 c0 = n0, c1 = n1, c2 = n2, c3 = n3;
        int nx = ib + 4;
        if (nx < i1) { n0 = PB8[nx]; n1 = PB8[nx + 1]; n2 = PB8[nx + 2]; n3 = PB8[nx + 3]; }
        #define STEP(cc, kk)  {                                                     \
            float lx = fmaxf(tb.x, cc[0]), ly = fmaxf(tb.y, cc[1]);                 \
            float rx = fminf(tb.z, cc[2]), ry = fminf(tb.w, cc[3]);                 \
            float wx = fmaxf(rx - lx, 0.f), wy = fmaxf(ry - ly, 0.f);               \
            float inter = wx * wy;                                                  \
            float sum = ta + cc[4];                                                 \
            bool win = (inter * bS > bI * sum) && ((ib + kk) < i1);                 \
            bI   = win ? inter      : bI;                                           \
            bS   = win ? sum        : bS;                                           \
            bidx = win ? (ib + kk)  : bidx;                                         \
        }
        STEP(c0, 0) STEP(c1, 1) STEP(c2, 2) STEP(c3, 3)
        #undef STEP
    }

    if (j < nb && bI >= 0.f) {
        float iou = bI / (bS - bI);          // precise divide, once per lane per chunk
        unsigned long long key =
            ((unsigned long long)__float_as_uint(iou) << 32) |
            (unsigned long long)(0xFFFFFFFFu - (unsigned)bidx);
        atomicMax(&maxkey[j], key);          // bigger iou wins; ties -> smaller idx
    }
}

// final: read per-j winner, box/conf losses, reduce, ACQ_REL election, write scalar.
// Reference gathers BOTH boxes by the argmax index: BPg=BP[idx], BTg=BT[idx].
__global__ void k_final(const float8* __restrict__ PB8, const float4* __restrict__ BT4,
                        const int* __restrict__ ctr,
                        const unsigned long long* __restrict__ maxkey,
                        float* __restrict__ acc, int* __restrict__ finalCtr,
                        float* __restrict__ out, float inv_batch) {
    int nb = 2 * (*ctr); if (nb > MAXB) nb = MAXB;
    int tid = threadIdx.x;
    int j = blockIdx.x * 256 + tid;
    float sxywh = 0.f, sobj = 0.f;
    if (j < nb) {
        unsigned long long key = maxkey[j];
        float iou = __uint_as_float((unsigned)(key >> 32));
        unsigned idx = 0xFFFFFFFFu - (unsigned)(key & 0xFFFFFFFFull);
        float8 pb = PB8[idx];
        float4 bt = BT4[idx];                // by idx, matching the reference
        float dx = pb[0] - bt.x, dy = pb[1] - bt.y;
        float dw = sqrtf(pb[2]) - sqrtf(bt.z);
        float dh = sqrtf(pb[3]) - sqrtf(bt.w);
        sxywh = dx * dx + dy * dy + dw * dw + dh * dh;
        float dob = pb[5] - iou;
        sobj = dob * dob;
    }
    #pragma unroll
    for (int o = 32; o; o >>= 1) { sxywh += __shfl_down(sxywh, o); sobj += __shfl_down(sobj, o); }
    if ((tid & 63) == 0) {
        if (sxywh != 0.f) atomicAdd(&acc[0], sxywh);
        if (sobj != 0.f)  atomicAdd(&acc[1], sobj);
    }
    __syncthreads();                         // drains wave-leader atomics
    if (tid == 0) {
        int old = __hip_atomic_fetch_add(finalCtr, 1, __ATOMIC_ACQ_REL, __HIP_MEMORY_SCOPE_AGENT);
        if (old == NTILE - 1) {              // last block: all adds visible
            float a0 = __hip_atomic_load(&acc[0], __ATOMIC_RELAXED, __HIP_MEMORY_SCOPE_AGENT);
            float a1 = __hip_atomic_load(&acc[1], __ATOMIC_RELAXED, __HIP_MEMORY_SCOPE_AGENT);
            float a2 = __hip_atomic_load(&acc[2], __ATOMIC_RELAXED, __HIP_MEMORY_SCOPE_AGENT);
            float a3 = __hip_atomic_load(&acc[3], __ATOMIC_RELAXED, __HIP_MEMORY_SCOPE_AGENT);
            out[0] = (5.0f * a0 + 0.5f * a2 + a1 + a3) * inv_batch;
        }
    }
}

extern "C" void kernel_launch(void* const* d_in, const int* in_sizes, int n_in,
                              void* d_out, int out_size, void* d_ws, size_t ws_size,
                              hipStream_t stream) {
    const float* P = (const float*)d_in[0];
    const float* T = (const float*)d_in[1];
    int ncell = in_sizes[0] / N_CH;                 // 25088
    int batch = ncell / (S_GRID * S_GRID);          // 512

    char* ws = (char*)d_ws;
    float* acc      = (float*)ws;
    int*   ctr      = (int*)(ws + 16);
    int*   finalCtr = (int*)(ws + 20);
    unsigned long long* maxkey = (unsigned long long*)(ws + 1024);
    float8* PB8 = (float8*)(ws + 66560);
    float4* BT4 = (float4*)(ws + 328704);

    int nblk = (ncell + 255) / 256;                 // 98
    k_init <<<1, 64, 0, stream>>>(acc, ctr, finalCtr);
    k_prep <<<nblk, 256, 0, stream>>>(P, T, ncell, ctr, PB8, BT4, acc, maxkey);
    dim3 g3(NTILE, NCHUNK);                         // (32, 80); inactive blocks exit
    k_match<<<g3, 256, 0, stream>>>(PB8, BT4, ctr, maxkey);
    k_final<<<NTILE, 256, 0, stream>>>(PB8, BT4, ctr, maxkey, acc, finalCtr,
                                       (float*)d_out, 1.0f / (float)batch);
}

// Round 14
// 57.494 us; speedup vs baseline: 1.1943x; 1.0292x over previous
//
#include <hip/hip_runtime.h>
#include <stdint.h>

#define S_GRID 7
#define N_CH 30
#define MAXB 8192          // max compacted boxes (actual data: 6272)
#define NTILE 32           // j-tiles (256 cols each)
#define NCHUNK 80          // i-chunks in match
#define CHUNK_MAX 104      // ceil(MAXB/NCHUNK) aligned to 4

// ---- ws layout (bytes) ----
// 0      : float acc[4] {xy+wh, obj, nobj, class}
// 16     : int ctr        (obj-cell allocator)
// 20     : int finalCtr
// 1024   : u64 maxkey[MAXB]   (65536)  -> 66560
// 66560  : float4 PB4[MAXB]   (131072) -> 197632   {x0,y0,x1,y1}
// 197632 : float4 BT4[MAXB]   (131072) -> 328704
// 328704 : float  ConfP[MAXB] (32768)  -> 361472

__global__ void k_init(float* __restrict__ acc, int* __restrict__ ctr, int* __restrict__ finalCtr) {
    if (threadIdx.x < 4)  acc[threadIdx.x] = 0.0f;
    if (threadIdx.x == 4) *ctr = 0;
    if (threadIdx.x == 5) *finalCtr = 0;
}

// one pass over P,T: unordered compaction (wave-aggregated atomic alloc; absmax=0 R4/R10/R12/R13)
// + cheap masked losses into pre-zeroed acc + maxkey zeroing. float2 row loads.
__global__ void k_prep(const float* __restrict__ P, const float* __restrict__ T, int ncell,
                       int* __restrict__ ctr,
                       float4* __restrict__ PB4, float4* __restrict__ BT4,
                       float* __restrict__ ConfP,
                       float* __restrict__ acc,
                       unsigned long long* __restrict__ maxkey) {
    int gid = blockIdx.x * 256 + threadIdx.x;
    if (gid < MAXB) maxkey[gid] = 0ull;      // plain store; visible to k_match at boundary

    int cell = gid;
    float2 pr[15], tr[15];
    if (cell < ncell) {
        const float2* p2 = (const float2*)(P + (size_t)cell * N_CH);
        const float2* t2 = (const float2*)(T + (size_t)cell * N_CH);
        #pragma unroll
        for (int k = 0; k < 15; ++k) { pr[k] = p2[k]; tr[k] = t2[k]; }
    } else {
        #pragma unroll
        for (int k = 0; k < 15; ++k) { pr[k] = make_float2(0.f, 0.f); tr[k] = make_float2(0.f, 0.f); }
    }
    bool obj = (cell < ncell) && (tr[2].x == 1.0f);   // t[4]

    int lane = threadIdx.x & 63;
    unsigned long long bm = __ballot(obj);
    int wcnt = __popcll(bm);
    int base = 0;
    if (lane == 0 && wcnt) base = atomicAdd(ctr, wcnt);
    base = __shfl(base, 0);

    float cls = 0.f, nob = 0.f;
    if (cell < ncell) {
        if (obj) {
            #pragma unroll
            for (int k = 5; k < 15; ++k) {            // floats 10..29
                float d0 = pr[k].x - tr[k].x, d1 = pr[k].y - tr[k].y;
                cls += d0 * d0 + d1 * d1;
            }
        } else {
            float d0 = pr[2].x - tr[2].x;             // p[4]-t[4]
            float d1 = pr[4].y - tr[4].y;             // p[9]-t[9]
            nob = d0 * d0 + d1 * d1;
        }
    }
    #pragma unroll
    for (int o = 32; o; o >>= 1) { cls += __shfl_down(cls, o); nob += __shfl_down(nob, o); }
    if (lane == 0) {
        if (cls != 0.f) atomicAdd(&acc[3], cls);
        if (nob != 0.f) atomicAdd(&acc[2], nob);
    }

    if (obj) {
        int rank = base + __popcll(bm & ((1ull << lane) - 1ull));
        float bx[2][5] = {
            { pr[0].x, pr[0].y, pr[1].x, pr[1].y, pr[2].x },
            { pr[2].y, pr[3].x, pr[3].y, pr[4].x, pr[4].y }
        };
        float tx[2][4] = {
            { tr[0].x, tr[0].y, tr[1].x, tr[1].y },
            { tr[2].y, tr[3].x, tr[3].y, tr[4].x }
        };
        #pragma unroll
        for (int bb = 0; bb < 2; ++bb) {
            int m = 2 * rank + bb;
            if (m < MAXB) {
                float cx = bx[bb][0] / (float)S_GRID, cy = bx[bb][1] / (float)S_GRID;
                float w = bx[bb][2], h = bx[bb][3];
                PB4[m] = make_float4(cx - 0.5f * w, cy - 0.5f * h, cx + 0.5f * w, cy + 0.5f * h);
                ConfP[m] = bx[bb][4];
                cx = tx[bb][0] / (float)S_GRID; cy = tx[bb][1] / (float)S_GRID;
                w = tx[bb][2]; h = tx[bb][3];
                BT4[m] = make_float4(cx - 0.5f * w, cy - 0.5f * h, cx + 0.5f * w, cy + 0.5f * h);
            }
        }
    }
}

// j-per-LANE match with LDS-staged i-chunk:
//  - block stages its chunk once (coalesced, L2-resident) into LDS
//  - waves stream boxes via wave-uniform ds_read_b128 (broadcast, conflict-free)
//  - branchless, division-free argmax: iou_i > iou_best <=> inter_i*bS > bI*sum_i
__global__ void k_match(const float4* __restrict__ PB4, const float4* __restrict__ BT4,
                        const int* __restrict__ ctr,
                        unsigned long long* __restrict__ maxkey) {
    __shared__ float4 sh[CHUNK_MAX];
    int nb = 2 * (*ctr); if (nb > MAXB) nb = MAXB;
    int tid = threadIdx.x;
    int j = blockIdx.x * 256 + tid;
    if (blockIdx.x * 256 >= nb) return;      // whole tile beyond nb
    int c = blockIdx.y;
    int chunkLen = (((nb + NCHUNK - 1) / NCHUNK) + 3) & ~3;   // multiple of 4, <= CHUNK_MAX
    int i0 = c * chunkLen;
    int i1 = min(nb, i0 + chunkLen);
    if (i0 >= i1) return;

    int len = i1 - i0;
    int padded = (len + 3) & ~3;
    for (int k = tid; k < padded; k += 256)   // one pass (padded <= 104 < 256)
        sh[k] = (k < len) ? PB4[i0 + k] : make_float4(0.f, 0.f, 0.f, 0.f);
    __syncthreads();

    float4 tb = BT4[min(j, nb - 1)];          // per-lane target box
    float ta = (tb.z - tb.x) * (tb.w - tb.y);
    float bI = -1.f, bS = 1.f;                // first valid box always wins
    int bidx = 0;

    for (int kb = 0; kb < padded; kb += 4) {
        float4 b0 = sh[kb], b1 = sh[kb + 1], b2 = sh[kb + 2], b3 = sh[kb + 3];
        #define STEP(bb, kk)  {                                                     \
            float lx = fmaxf(tb.x, bb.x), ly = fmaxf(tb.y, bb.y);                   \
            float rx = fminf(tb.z, bb.z), ry = fminf(tb.w, bb.w);                   \
            float wx = fmaxf(rx - lx, 0.f), wy = fmaxf(ry - ly, 0.f);               \
            float inter = wx * wy;                                                  \
            float area = (bb.z - bb.x) * (bb.w - bb.y);                             \
            float sum = ta + area;                                                  \
            bool win = (inter * bS > bI * sum) && ((kb + kk) < len);                \
            bI   = win ? inter          : bI;                                       \
            bS   = win ? sum            : bS;                                       \
            bidx = win ? (i0 + kb + kk) : bidx;                                     \
        }
        STEP(b0, 0) STEP(b1, 1) STEP(b2, 2) STEP(b3, 3)
        #undef STEP
    }

    if (j < nb && bI >= 0.f) {
        float iou = bI / (bS - bI);          // precise divide, once per lane per chunk
        unsigned long long key =
            ((unsigned long long)__float_as_uint(iou) << 32) |
            (unsigned long long)(0xFFFFFFFFu - (unsigned)bidx);
        atomicMax(&maxkey[j], key);          // bigger iou wins; ties -> smaller idx
    }
}

// final: read per-j winner, box/conf losses, reduce, ACQ_REL election, write scalar.
// Reference gathers BOTH boxes by the argmax index: BPg=BP[idx], BTg=BT[idx].
__global__ void k_final(const float4* __restrict__ PB4, const float4* __restrict__ BT4,
                        const float* __restrict__ ConfP,
                        const int* __restrict__ ctr,
                        const unsigned long long* __restrict__ maxkey,
                        float* __restrict__ acc, int* __restrict__ finalCtr,
                        float* __restrict__ out, float inv_batch) {
    int nb = 2 * (*ctr); if (nb > MAXB) nb = MAXB;
    int tid = threadIdx.x;
    int j = blockIdx.x * 256 + tid;
    float sxywh = 0.f, sobj = 0.f;
    if (j < nb) {
        unsigned long long key = maxkey[j];
        float iou = __uint_as_float((unsigned)(key >> 32));
        unsigned idx = 0xFFFFFFFFu - (unsigned)(key & 0xFFFFFFFFull);
        float4 bp = PB4[idx];
        float4 bt = BT4[idx];                // by idx, matching the reference
        float cp = ConfP[idx];
        float dx = bp.x - bt.x, dy = bp.y - bt.y;
        float dw = sqrtf(bp.z) - sqrtf(bt.z);
        float dh = sqrtf(bp.w) - sqrtf(bt.w);
        sxywh = dx * dx + dy * dy + dw * dw + dh * dh;
        float dob = cp - iou;
        sobj = dob * dob;
    }
    #pragma unroll
    for (int o = 32; o; o >>= 1) { sxywh += __shfl_down(sxywh, o); sobj += __shfl_down(sobj, o); }
    if ((tid & 63) == 0) {
        if (sxywh != 0.f) atomicAdd(&acc[0], sxywh);
        if (sobj != 0.f)  atomicAdd(&acc[1], sobj);
    }
    __syncthreads();                         // drains wave-leader atomics
    if (tid == 0) {
        int old = __hip_atomic_fetch_add(finalCtr, 1, __ATOMIC_ACQ_REL, __HIP_MEMORY_SCOPE_AGENT);
        if (old == NTILE - 1) {              // last block: all adds visible
            float a0 = __hip_atomic_load(&acc[0], __ATOMIC_RELAXED, __HIP_MEMORY_SCOPE_AGENT);
            float a1 = __hip_atomic_load(&acc[1], __ATOMIC_RELAXED, __HIP_MEMORY_SCOPE_AGENT);
            float a2 = __hip_atomic_load(&acc[2], __ATOMIC_RELAXED, __HIP_MEMORY_SCOPE_AGENT);
            float a3 = __hip_atomic_load(&acc[3], __ATOMIC_RELAXED, __HIP_MEMORY_SCOPE_AGENT);
            out[0] = (5.0f * a0 + 0.5f * a2 + a1 + a3) * inv_batch;
        }
    }
}

extern "C" void kernel_launch(void* const* d_in, const int* in_sizes, int n_in,
                              void* d_out, int out_size, void* d_ws, size_t ws_size,
                              hipStream_t stream) {
    const float* P = (const float*)d_in[0];
    const float* T = (const float*)d_in[1];
    int ncell = in_sizes[0] / N_CH;                 // 25088
    int batch = ncell / (S_GRID * S_GRID);          // 512

    char* ws = (char*)d_ws;
    float* acc      = (float*)ws;
    int*   ctr      = (int*)(ws + 16);
    int*   finalCtr = (int*)(ws + 20);
    unsigned long long* maxkey = (unsigned long long*)(ws + 1024);
    float4* PB4  = (float4*)(ws + 66560);
    float4* BT4  = (float4*)(ws + 197632);
    float*  ConfP = (float*)(ws + 328704);

    int nblk = (ncell + 255) / 256;                 // 98
    k_init <<<1, 64, 0, stream>>>(acc, ctr, finalCtr);
    k_prep <<<nblk, 256, 0, stream>>>(P, T, ncell, ctr, PB4, BT4, ConfP, acc, maxkey);
    dim3 g3(NTILE, NCHUNK);                         // (32, 80); inactive blocks exit
    k_match<<<g3, 256, 0, stream>>>(PB4, BT4, ctr, maxkey);
    k_final<<<NTILE, 256, 0, stream>>>(PB4, BT4, ConfP, ctr, maxkey, acc, finalCtr,
                                       (float*)d_out, 1.0f / (float)batch);
}